// Round 9
// baseline (117.582 us; speedup 1.0000x reference)
//
#include <hip/hip_runtime.h>
#include <stdint.h>

#define D_FEAT 128
#define H1 18
#define H2 32
#define EPS 1e-8f

typedef float f32x4 __attribute__((ext_vector_type(4)));

__device__ __forceinline__ uint32_t f32_to_bf16_rne(float f) {
    uint32_t u = __float_as_uint(f);
    return (u + 0x7fffu + ((u >> 16) & 1u)) >> 16;
}
__device__ __forceinline__ float bf16lo(uint32_t v) { return __uint_as_float(v << 16); }
__device__ __forceinline__ float bf16hi(uint32_t v) { return __uint_as_float(v & 0xffff0000u); }

__device__ __forceinline__ float dot8(uint4 s, uint4 t) {
    float d;
    d  = bf16lo(s.x) * bf16lo(t.x);
    d  = fmaf(bf16hi(s.x), bf16hi(t.x), d);
    d  = fmaf(bf16lo(s.y), bf16lo(t.y), d);
    d  = fmaf(bf16hi(s.y), bf16hi(t.y), d);
    d  = fmaf(bf16lo(s.z), bf16lo(t.z), d);
    d  = fmaf(bf16hi(s.z), bf16hi(t.z), d);
    d  = fmaf(bf16lo(s.w), bf16lo(t.w), d);
    d  = fmaf(bf16hi(s.w), bf16hi(t.w), d);
    return d;
}

// ---------- prep: x[f32,N,128] -> NORMALIZED packed bf16 [N,32 uint2] ----------
__global__ __launch_bounds__(256) void prep_kernel(
    const float* __restrict__ x,
    uint2* __restrict__ xb,
    int n_nodes)
{
    const int lane = threadIdx.x & 63;
    const int sub = lane & 31;
    const int half = lane >> 5;
    const int wavesPerBlock = blockDim.x >> 6;
    const long long wv = (long long)blockIdx.x * wavesPerBlock + (threadIdx.x >> 6);
    const int node = (int)(2 * wv + half);
    if (node >= n_nodes) return;

    const f32x4 v = __builtin_nontemporal_load(
        reinterpret_cast<const f32x4*>(x + (size_t)node * D_FEAT) + sub);
    float ss = v[0] * v[0] + v[1] * v[1] + v[2] * v[2] + v[3] * v[3];
    #pragma unroll
    for (int m = 16; m >= 1; m >>= 1) ss += __shfl_xor(ss, m);
    const float r = 1.0f / fmaxf(sqrtf(ss), EPS);
    uint2 p;
    p.x = (f32_to_bf16_rne(v[1] * r) << 16) | f32_to_bf16_rne(v[0] * r);
    p.y = (f32_to_bf16_rne(v[3] * r) << 16) | f32_to_bf16_rne(v[2] * r);
    xb[(size_t)node * 32 + sub] = p;
}

// ---------- main: 2 bursts/wave, 2-batch rotating gather pipeline, 8 waves/SIMD ----------
__global__ __launch_bounds__(256, 8) void edge_kernel(
    const uint4* __restrict__ xb,       // [N][16] (8 bf16 per uint4)
    const int* __restrict__ edge_index, // [2, E]
    const float* __restrict__ edge_attr,
    const float* __restrict__ W1, const float* __restrict__ b1,
    const float* __restrict__ W2, const float* __restrict__ b2,
    float* __restrict__ out, int n_edges)
{
    __shared__ int sIdx[4][2][64];
    __shared__ int tIdx[4][2][64];
    __shared__ float dotb[4][64];

    const int lane = threadIdx.x & 63;
    const int w = threadIdx.x >> 6;
    const int g = lane >> 4;
    const int k = lane & 15;
    const long long nBursts = ((long long)n_edges + 63) >> 6;
    const long long waveId = (long long)blockIdx.x * 4 + w;
    const long long bu0 = waveId * 2;
    const long long bu1 = bu0 + 1;
    if (bu0 >= nBursts) return;
    const bool have1 = bu1 < nBursts;

    const f32x4* __restrict__ eav = reinterpret_cast<const f32x4*>(edge_attr);
    const f32x4* __restrict__ W2v = reinterpret_cast<const f32x4*>(W2);
    const f32x4* __restrict__ b2v = reinterpret_cast<const f32x4*>(b2);

    // ---- stage burst0 indices + attr ----
    const long long e0 = (bu0 << 6) + lane;
    const bool act0 = e0 < (long long)n_edges;
    f32x4 attr0 = (f32x4)0.f;
    {
        int sL = 0, tL = 0;
        if (act0) {
            sL = edge_index[e0];
            tL = edge_index[(long long)n_edges + e0];
            attr0 = eav[e0];
        }
        sIdx[w][0][lane] = sL;
        tIdx[w][0][lane] = tL;
    }

    // 2-batch rotating buffers: P = {pS0,pT0,pS1,pT1}, Q likewise (8 uint4 total)
    uint4 pS0, pT0, pS1, pT1, qS0, qT0, qS1, qT1;

    #define LOAD2(A, B, C, D, BASE, BUF) {                                \
        const int eg0_ = (BASE) * 4 + g;                                  \
        const int eg1_ = (BASE + 1) * 4 + g;                              \
        A = xb[(size_t)sIdx[w][BUF][eg0_] * 16 + k];                      \
        B = xb[(size_t)tIdx[w][BUF][eg0_] * 16 + k];                      \
        C = xb[(size_t)sIdx[w][BUF][eg1_] * 16 + k];                      \
        D = xb[(size_t)tIdx[w][BUF][eg1_] * 16 + k];                      \
    }
    #define CONS2(A, B, C, D, BASE) {                                     \
        const int eg0_ = (BASE) * 4 + g;                                  \
        const int eg1_ = (BASE + 1) * 4 + g;                              \
        float d0 = dot8(A, B);                                            \
        float d1 = dot8(C, D);                                            \
        d0 += __shfl_xor(d0, 1);  d1 += __shfl_xor(d1, 1);                \
        d0 += __shfl_xor(d0, 2);  d1 += __shfl_xor(d1, 2);                \
        d0 += __shfl_xor(d0, 4);  d1 += __shfl_xor(d1, 4);                \
        d0 += __shfl_xor(d0, 8);  d1 += __shfl_xor(d1, 8);                \
        if (k == 0) { dotb[w][eg0_] = d0; dotb[w][eg1_] = d1; }           \
    }
    #define MLP_STORE(ATTR, ACT, E)                                       \
        {                                                                 \
            const float cosv = dotb[w][lane];                             \
            float h[H1];                                                  \
            _Pragma("unroll") for (int i = 0; i < H1; ++i) {              \
                float v = b1[i];                                          \
                v = fmaf(ATTR[0], W1[0 * H1 + i], v);                     \
                v = fmaf(ATTR[1], W1[1 * H1 + i], v);                     \
                v = fmaf(ATTR[2], W1[2 * H1 + i], v);                     \
                v = fmaf(ATTR[3], W1[3 * H1 + i], v);                     \
                v = fmaf(cosv,    W1[4 * H1 + i], v);                     \
                h[i] = fmaxf(v, 0.f);                                     \
            }                                                             \
            if (ACT) {                                                    \
                f32x4* op = reinterpret_cast<f32x4*>(out + (size_t)(E) * H2); \
                _Pragma("unroll") for (int jg = 0; jg < 8; ++jg) {        \
                    f32x4 a = b2v[jg];                                    \
                    _Pragma("unroll") for (int i = 0; i < H1; ++i)        \
                        a += h[i] * W2v[i * 8 + jg];                      \
                    _Pragma("unroll") for (int c = 0; c < 4; ++c)         \
                        a[c] = fmaxf(a[c], 0.f);                          \
                    op[jg] = a;                                           \
                }                                                         \
            }                                                             \
        }

    // ---- burst0: prime pipeline ----
    LOAD2(pS0, pT0, pS1, pT1, 0, 0)
    LOAD2(qS0, qT0, qS1, qT1, 2, 0)

    // ---- prefetch burst1 indices + attr while gathers are in flight ----
    const long long e1 = (bu1 << 6) + lane;
    const bool act1 = have1 && (e1 < (long long)n_edges);
    f32x4 attr1 = (f32x4)0.f;
    if (have1) {
        int sL = 0, tL = 0;
        if (act1) {
            sL = edge_index[e1];
            tL = edge_index[(long long)n_edges + e1];
            attr1 = eav[e1];
        }
        sIdx[w][1][lane] = sL;
        tIdx[w][1][lane] = tL;
    }

    // ---- burst0: rotate consume/load ----
    CONS2(pS0, pT0, pS1, pT1, 0)   LOAD2(pS0, pT0, pS1, pT1, 4, 0)
    CONS2(qS0, qT0, qS1, qT1, 2)   LOAD2(qS0, qT0, qS1, qT1, 6, 0)
    CONS2(pS0, pT0, pS1, pT1, 4)   LOAD2(pS0, pT0, pS1, pT1, 8, 0)
    CONS2(qS0, qT0, qS1, qT1, 6)   LOAD2(qS0, qT0, qS1, qT1, 10, 0)
    CONS2(pS0, pT0, pS1, pT1, 8)   LOAD2(pS0, pT0, pS1, pT1, 12, 0)
    CONS2(qS0, qT0, qS1, qT1, 10)  LOAD2(qS0, qT0, qS1, qT1, 14, 0)
    CONS2(pS0, pT0, pS1, pT1, 12)
    if (have1) { LOAD2(pS0, pT0, pS1, pT1, 0, 1) }   // burst1 batch0 in flight
    CONS2(qS0, qT0, qS1, qT1, 14)

    // ---- burst0 MLP + store (hides burst1 batch0 latency) ----
    MLP_STORE(attr0, act0, e0)

    if (!have1) return;

    // ---- burst1: rotate ----
    LOAD2(qS0, qT0, qS1, qT1, 2, 1)
    CONS2(pS0, pT0, pS1, pT1, 0)   LOAD2(pS0, pT0, pS1, pT1, 4, 1)
    CONS2(qS0, qT0, qS1, qT1, 2)   LOAD2(qS0, qT0, qS1, qT1, 6, 1)
    CONS2(pS0, pT0, pS1, pT1, 4)   LOAD2(pS0, pT0, pS1, pT1, 8, 1)
    CONS2(qS0, qT0, qS1, qT1, 6)   LOAD2(qS0, qT0, qS1, qT1, 10, 1)
    CONS2(pS0, pT0, pS1, pT1, 8)   LOAD2(pS0, pT0, pS1, pT1, 12, 1)
    CONS2(qS0, qT0, qS1, qT1, 10)  LOAD2(qS0, qT0, qS1, qT1, 14, 1)
    CONS2(pS0, pT0, pS1, pT1, 12)
    CONS2(qS0, qT0, qS1, qT1, 14)

    MLP_STORE(attr1, act1, e1)

    #undef LOAD2
    #undef CONS2
    #undef MLP_STORE
}

// ---------- fallback (fp32 direct, known-good from round 1) ----------
__device__ __forceinline__ float mlp_out32(
    const float4 ea, float cosv,
    const float* __restrict__ sW1, const float* __restrict__ sb1,
    const float* __restrict__ sW2, const float* __restrict__ sb2,
    int sub, int base)
{
    const float f[5] = { ea.x, ea.y, ea.z, ea.w, cosv };
    float hval = 0.f;
    if (sub < H1) {
        hval = sb1[sub];
        #pragma unroll
        for (int kk = 0; kk < 5; ++kk) hval = fmaf(f[kk], sW1[kk * H1 + sub], hval);
        hval = fmaxf(hval, 0.f);
    }
    float acc = sb2[sub];
    #pragma unroll
    for (int i = 0; i < H1; ++i)
        acc = fmaf(__shfl(hval, base + i), sW2[i * H2 + sub], acc);
    return fmaxf(acc, 0.f);
}

__global__ __launch_bounds__(256) void edge_encoder_fp32(
    const float* __restrict__ x,
    const int* __restrict__ edge_index,
    const float* __restrict__ edge_attr,
    const float* __restrict__ W1, const float* __restrict__ b1,
    const float* __restrict__ W2, const float* __restrict__ b2,
    float* __restrict__ out, int n_edges)
{
    __shared__ float sW1[5 * H1];
    __shared__ float sb1[H1];
    __shared__ float sW2[H1 * H2];
    __shared__ float sb2[H2];
    for (int i = threadIdx.x; i < 5 * H1; i += blockDim.x) sW1[i] = W1[i];
    for (int i = threadIdx.x; i < H1; i += blockDim.x) sb1[i] = b1[i];
    for (int i = threadIdx.x; i < H1 * H2; i += blockDim.x) sW2[i] = W2[i];
    for (int i = threadIdx.x; i < H2; i += blockDim.x) sb2[i] = b2[i];
    __syncthreads();

    const int lane = threadIdx.x & 63;
    const int sub = lane & 31;
    const int base = lane & 32;
    const int wavesPerBlock = blockDim.x >> 6;
    const int waveId = blockIdx.x * wavesPerBlock + (threadIdx.x >> 6);
    const int totalWaves = gridDim.x * wavesPerBlock;

    for (long long gg = waveId; 2 * gg < (long long)n_edges; gg += totalWaves) {
        const long long e = 2 * gg + (lane >> 5);
        const bool active = (e < (long long)n_edges);
        float dot = 0.f, ss = 0.f, tt = 0.f;
        float4 ea = make_float4(0.f, 0.f, 0.f, 0.f);
        if (active) {
            const int srcN = edge_index[e];
            const int tgtN = edge_index[(long long)n_edges + e];
            const float4 s4 = *reinterpret_cast<const float4*>(
                x + (size_t)srcN * D_FEAT + (size_t)sub * 4);
            const float4 t4 = *reinterpret_cast<const float4*>(
                x + (size_t)tgtN * D_FEAT + (size_t)sub * 4);
            dot = s4.x * t4.x + s4.y * t4.y + s4.z * t4.z + s4.w * t4.w;
            ss  = s4.x * s4.x + s4.y * s4.y + s4.z * s4.z + s4.w * s4.w;
            tt  = t4.x * t4.x + t4.y * t4.y + t4.z * t4.z + t4.w * t4.w;
            ea = *reinterpret_cast<const float4*>(edge_attr + e * 4);
        }
        #pragma unroll
        for (int m = 16; m >= 1; m >>= 1) {
            dot += __shfl_xor(dot, m);
            ss  += __shfl_xor(ss, m);
            tt  += __shfl_xor(tt, m);
        }
        const float cosv = dot / (fmaxf(sqrtf(ss), EPS) * fmaxf(sqrtf(tt), EPS));
        const float o = mlp_out32(ea, cosv, sW1, sb1, sW2, sb2, sub, base);
        if (active) out[e * H2 + sub] = o;
    }
}

extern "C" void kernel_launch(void* const* d_in, const int* in_sizes, int n_in,
                              void* d_out, int out_size, void* d_ws, size_t ws_size,
                              hipStream_t stream) {
    const float* x         = (const float*)d_in[0];
    const int*   edge_idx  = (const int*)d_in[1];
    const float* edge_attr = (const float*)d_in[2];
    const float* W1        = (const float*)d_in[3];
    const float* b1        = (const float*)d_in[4];
    const float* W2        = (const float*)d_in[5];
    const float* b2        = (const float*)d_in[6];
    float* out = (float*)d_out;

    const int n_nodes = in_sizes[0] / D_FEAT;
    const int n_edges = in_sizes[1] / 2;

    const size_t xb_bytes = (size_t)n_nodes * (D_FEAT / 2) * sizeof(uint32_t);

    if (ws_size >= xb_bytes) {
        uint2* xb = (uint2*)d_ws;
        const int block = 256;
        const int prep_grid = (n_nodes + 7) / 8;   // 2 nodes/wave, 8/block
        prep_kernel<<<prep_grid, block, 0, stream>>>(x, xb, n_nodes);

        const long long nBursts = ((long long)n_edges + 63) >> 6;
        const long long nWaves = (nBursts + 1) / 2;   // exactly 2 bursts/wave
        const int grid = (int)((nWaves + 3) / 4);
        edge_kernel<<<grid, block, 0, stream>>>(
            (const uint4*)xb, edge_idx, edge_attr,
            W1, b1, W2, b2, out, n_edges);
    } else {
        edge_encoder_fp32<<<2048, 256, 0, stream>>>(
            x, edge_idx, edge_attr, W1, b1, W2, b2, out, n_edges);
    }
}

// Round 10
// 100.441 us; speedup vs baseline: 1.1707x; 1.1707x over previous
//
#include <hip/hip_runtime.h>
#include <stdint.h>

#define D_FEAT 128
#define H1 18
#define H2 32
#define EPS 1e-8f

typedef float f32x4 __attribute__((ext_vector_type(4)));

__device__ __forceinline__ uint32_t f32_to_bf16_rne(float f) {
    uint32_t u = __float_as_uint(f);
    return (u + 0x7fffu + ((u >> 16) & 1u)) >> 16;
}
__device__ __forceinline__ float bf16lo(uint32_t v) { return __uint_as_float(v << 16); }
__device__ __forceinline__ float bf16hi(uint32_t v) { return __uint_as_float(v & 0xffff0000u); }

__device__ __forceinline__ float dot8(uint4 s, uint4 t) {
    float d;
    d  = bf16lo(s.x) * bf16lo(t.x);
    d  = fmaf(bf16hi(s.x), bf16hi(t.x), d);
    d  = fmaf(bf16lo(s.y), bf16lo(t.y), d);
    d  = fmaf(bf16hi(s.y), bf16hi(t.y), d);
    d  = fmaf(bf16lo(s.z), bf16lo(t.z), d);
    d  = fmaf(bf16hi(s.z), bf16hi(t.z), d);
    d  = fmaf(bf16lo(s.w), bf16lo(t.w), d);
    d  = fmaf(bf16hi(s.w), bf16hi(t.w), d);
    return d;
}

// ---------- prep: x[f32,N,128] -> NORMALIZED packed bf16 [N,32 uint2] ----------
__global__ __launch_bounds__(256) void prep_kernel(
    const float* __restrict__ x,
    uint2* __restrict__ xb,
    int n_nodes)
{
    const int lane = threadIdx.x & 63;
    const int sub = lane & 31;
    const int half = lane >> 5;
    const int wavesPerBlock = blockDim.x >> 6;
    const long long wv = (long long)blockIdx.x * wavesPerBlock + (threadIdx.x >> 6);
    const int node = (int)(2 * wv + half);
    if (node >= n_nodes) return;

    const f32x4 v = __builtin_nontemporal_load(
        reinterpret_cast<const f32x4*>(x + (size_t)node * D_FEAT) + sub);
    float ss = v[0] * v[0] + v[1] * v[1] + v[2] * v[2] + v[3] * v[3];
    #pragma unroll
    for (int m = 16; m >= 1; m >>= 1) ss += __shfl_xor(ss, m);
    const float r = 1.0f / fmaxf(sqrtf(ss), EPS);
    uint2 p;
    p.x = (f32_to_bf16_rne(v[1] * r) << 16) | f32_to_bf16_rne(v[0] * r);
    p.y = (f32_to_bf16_rne(v[3] * r) << 16) | f32_to_bf16_rne(v[2] * r);
    xb[(size_t)node * 32 + sub] = p;
}

// ---------- main: R8 skeleton + weights in LDS ----------
__global__ __launch_bounds__(256) void edge_kernel(
    const uint4* __restrict__ xb,       // [N][16] (8 bf16 per uint4)
    const int* __restrict__ edge_index, // [2, E]
    const float* __restrict__ edge_attr,
    const float* __restrict__ W1, const float* __restrict__ b1,
    const float* __restrict__ W2, const float* __restrict__ b2,
    float* __restrict__ out, int n_edges)
{
    __shared__ int sIdx[4][2][64];
    __shared__ int tIdx[4][2][64];
    __shared__ float dotb[4][64];
    __shared__ float sW1[5 * H1];
    __shared__ float sb1[H1];
    __shared__ float sW2[H1 * H2];   // [i][j] row-major, read as f32x4
    __shared__ float sb2[H2];

    // stage weights once per block (uniform ds_read broadcasts thereafter)
    for (int i = threadIdx.x; i < 5 * H1; i += blockDim.x) sW1[i] = W1[i];
    for (int i = threadIdx.x; i < H1; i += blockDim.x) sb1[i] = b1[i];
    for (int i = threadIdx.x; i < H1 * H2; i += blockDim.x) sW2[i] = W2[i];
    for (int i = threadIdx.x; i < H2; i += blockDim.x) sb2[i] = b2[i];
    __syncthreads();

    const int lane = threadIdx.x & 63;
    const int w = threadIdx.x >> 6;
    const int g = lane >> 4;
    const int k = lane & 15;
    const long long nBursts = ((long long)n_edges + 63) >> 6;
    const long long waveId = (long long)blockIdx.x * 4 + w;
    const long long bu0 = waveId * 2;
    const long long bu1 = bu0 + 1;
    if (bu0 >= nBursts) return;
    const bool have1 = bu1 < nBursts;

    const f32x4* __restrict__ eav = reinterpret_cast<const f32x4*>(edge_attr);
    const f32x4* __restrict__ sW2v = reinterpret_cast<const f32x4*>(sW2);
    const f32x4* __restrict__ sb2v = reinterpret_cast<const f32x4*>(sb2);

    // ---- stage burst0 indices + attr ----
    const long long e0 = (bu0 << 6) + lane;
    const bool act0 = e0 < (long long)n_edges;
    f32x4 attr0 = (f32x4)0.f;
    {
        int sL = 0, tL = 0;
        if (act0) {
            sL = edge_index[e0];
            tL = edge_index[(long long)n_edges + e0];
            attr0 = eav[e0];
        }
        sIdx[w][0][lane] = sL;
        tIdx[w][0][lane] = tL;
    }

    uint4 sA[4], tA[4], sB[4], tB[4];

    #define LOADB(BS, BT, BASE, BUF)                                      \
        _Pragma("unroll") for (int j = 0; j < 4; ++j) {                   \
            const int eg = (BASE + j) * 4 + g;                            \
            BS[j] = xb[(size_t)sIdx[w][BUF][eg] * 16 + k];                \
            BT[j] = xb[(size_t)tIdx[w][BUF][eg] * 16 + k];                \
        }
    #define CONSUME(BS, BT, BASE)                                         \
        _Pragma("unroll") for (int j = 0; j < 4; ++j) {                   \
            const int eg = (BASE + j) * 4 + g;                            \
            float d = dot8(BS[j], BT[j]);                                 \
            d += __shfl_xor(d, 1);                                        \
            d += __shfl_xor(d, 2);                                        \
            d += __shfl_xor(d, 4);                                        \
            d += __shfl_xor(d, 8);                                        \
            if (k == 0) dotb[w][eg] = d;                                  \
        }
    #define MLP_STORE(ATTR, ACT, E)                                       \
        {                                                                 \
            const float cosv = dotb[w][lane];                             \
            float h[H1];                                                  \
            _Pragma("unroll") for (int i = 0; i < H1; ++i) {              \
                float v = sb1[i];                                         \
                v = fmaf(ATTR[0], sW1[0 * H1 + i], v);                    \
                v = fmaf(ATTR[1], sW1[1 * H1 + i], v);                    \
                v = fmaf(ATTR[2], sW1[2 * H1 + i], v);                    \
                v = fmaf(ATTR[3], sW1[3 * H1 + i], v);                    \
                v = fmaf(cosv,    sW1[4 * H1 + i], v);                    \
                h[i] = fmaxf(v, 0.f);                                     \
            }                                                             \
            if (ACT) {                                                    \
                f32x4* op = reinterpret_cast<f32x4*>(out + (size_t)(E) * H2); \
                _Pragma("unroll") for (int jg = 0; jg < 8; ++jg) {        \
                    f32x4 a = sb2v[jg];                                   \
                    _Pragma("unroll") for (int i = 0; i < H1; ++i)        \
                        a += h[i] * sW2v[i * 8 + jg];                     \
                    _Pragma("unroll") for (int c = 0; c < 4; ++c)         \
                        a[c] = fmaxf(a[c], 0.f);                          \
                    op[jg] = a;                                           \
                }                                                         \
            }                                                             \
        }

    // ---- burst0: issue first 16 gathers ----
    LOADB(sA, tA, 0, 0)
    LOADB(sB, tB, 4, 0)

    // ---- prefetch burst1 indices + attr while gathers are in flight ----
    const long long e1 = (bu1 << 6) + lane;
    const bool act1 = have1 && (e1 < (long long)n_edges);
    f32x4 attr1 = (f32x4)0.f;
    if (have1) {
        int sL = 0, tL = 0;
        if (act1) {
            sL = edge_index[e1];
            tL = edge_index[(long long)n_edges + e1];
            attr1 = eav[e1];
        }
        sIdx[w][1][lane] = sL;
        tIdx[w][1][lane] = tL;
    }

    // ---- burst0: consume/issue pipeline ----
    CONSUME(sA, tA, 0)
    LOADB(sA, tA, 8, 0)
    CONSUME(sB, tB, 4)
    LOADB(sB, tB, 12, 0)
    CONSUME(sA, tA, 8)
    CONSUME(sB, tB, 12)

    // ---- burst1: issue first 16 gathers BEFORE burst0's MLP ----
    if (have1) {
        LOADB(sA, tA, 0, 1)
        LOADB(sB, tB, 4, 1)
    }

    // ---- burst0 MLP + store (hides burst1 gather latency) ----
    MLP_STORE(attr0, act0, e0)

    if (!have1) return;

    // ---- burst1: finish pipeline ----
    CONSUME(sA, tA, 0)
    LOADB(sA, tA, 8, 1)
    CONSUME(sB, tB, 4)
    LOADB(sB, tB, 12, 1)
    CONSUME(sA, tA, 8)
    CONSUME(sB, tB, 12)

    MLP_STORE(attr1, act1, e1)

    #undef LOADB
    #undef CONSUME
    #undef MLP_STORE
}

// ---------- fallback (fp32 direct, known-good from round 1) ----------
__device__ __forceinline__ float mlp_out32(
    const float4 ea, float cosv,
    const float* __restrict__ sW1, const float* __restrict__ sb1,
    const float* __restrict__ sW2, const float* __restrict__ sb2,
    int sub, int base)
{
    const float f[5] = { ea.x, ea.y, ea.z, ea.w, cosv };
    float hval = 0.f;
    if (sub < H1) {
        hval = sb1[sub];
        #pragma unroll
        for (int kk = 0; kk < 5; ++kk) hval = fmaf(f[kk], sW1[kk * H1 + sub], hval);
        hval = fmaxf(hval, 0.f);
    }
    float acc = sb2[sub];
    #pragma unroll
    for (int i = 0; i < H1; ++i)
        acc = fmaf(__shfl(hval, base + i), sW2[i * H2 + sub], acc);
    return fmaxf(acc, 0.f);
}

__global__ __launch_bounds__(256) void edge_encoder_fp32(
    const float* __restrict__ x,
    const int* __restrict__ edge_index,
    const float* __restrict__ edge_attr,
    const float* __restrict__ W1, const float* __restrict__ b1,
    const float* __restrict__ W2, const float* __restrict__ b2,
    float* __restrict__ out, int n_edges)
{
    __shared__ float sW1[5 * H1];
    __shared__ float sb1[H1];
    __shared__ float sW2[H1 * H2];
    __shared__ float sb2[H2];
    for (int i = threadIdx.x; i < 5 * H1; i += blockDim.x) sW1[i] = W1[i];
    for (int i = threadIdx.x; i < H1; i += blockDim.x) sb1[i] = b1[i];
    for (int i = threadIdx.x; i < H1 * H2; i += blockDim.x) sW2[i] = W2[i];
    for (int i = threadIdx.x; i < H2; i += blockDim.x) sb2[i] = b2[i];
    __syncthreads();

    const int lane = threadIdx.x & 63;
    const int sub = lane & 31;
    const int base = lane & 32;
    const int wavesPerBlock = blockDim.x >> 6;
    const int waveId = blockIdx.x * wavesPerBlock + (threadIdx.x >> 6);
    const int totalWaves = gridDim.x * wavesPerBlock;

    for (long long gg = waveId; 2 * gg < (long long)n_edges; gg += totalWaves) {
        const long long e = 2 * gg + (lane >> 5);
        const bool active = (e < (long long)n_edges);
        float dot = 0.f, ss = 0.f, tt = 0.f;
        float4 ea = make_float4(0.f, 0.f, 0.f, 0.f);
        if (active) {
            const int srcN = edge_index[e];
            const int tgtN = edge_index[(long long)n_edges + e];
            const float4 s4 = *reinterpret_cast<const float4*>(
                x + (size_t)srcN * D_FEAT + (size_t)sub * 4);
            const float4 t4 = *reinterpret_cast<const float4*>(
                x + (size_t)tgtN * D_FEAT + (size_t)sub * 4);
            dot = s4.x * t4.x + s4.y * t4.y + s4.z * t4.z + s4.w * t4.w;
            ss  = s4.x * s4.x + s4.y * s4.y + s4.z * s4.z + s4.w * s4.w;
            tt  = t4.x * t4.x + t4.y * t4.y + t4.z * t4.z + t4.w * t4.w;
            ea = *reinterpret_cast<const float4*>(edge_attr + e * 4);
        }
        #pragma unroll
        for (int m = 16; m >= 1; m >>= 1) {
            dot += __shfl_xor(dot, m);
            ss  += __shfl_xor(ss, m);
            tt  += __shfl_xor(tt, m);
        }
        const float cosv = dot / (fmaxf(sqrtf(ss), EPS) * fmaxf(sqrtf(tt), EPS));
        const float o = mlp_out32(ea, cosv, sW1, sb1, sW2, sb2, sub, base);
        if (active) out[e * H2 + sub] = o;
    }
}

extern "C" void kernel_launch(void* const* d_in, const int* in_sizes, int n_in,
                              void* d_out, int out_size, void* d_ws, size_t ws_size,
                              hipStream_t stream) {
    const float* x         = (const float*)d_in[0];
    const int*   edge_idx  = (const int*)d_in[1];
    const float* edge_attr = (const float*)d_in[2];
    const float* W1        = (const float*)d_in[3];
    const float* b1        = (const float*)d_in[4];
    const float* W2        = (const float*)d_in[5];
    const float* b2        = (const float*)d_in[6];
    float* out = (float*)d_out;

    const int n_nodes = in_sizes[0] / D_FEAT;
    const int n_edges = in_sizes[1] / 2;

    const size_t xb_bytes = (size_t)n_nodes * (D_FEAT / 2) * sizeof(uint32_t);

    if (ws_size >= xb_bytes) {
        uint2* xb = (uint2*)d_ws;
        const int block = 256;
        const int prep_grid = (n_nodes + 7) / 8;   // 2 nodes/wave, 8/block
        prep_kernel<<<prep_grid, block, 0, stream>>>(x, xb, n_nodes);

        const long long nBursts = ((long long)n_edges + 63) >> 6;
        const long long nWaves = (nBursts + 1) / 2;   // exactly 2 bursts/wave
        const int grid = (int)((nWaves + 3) / 4);
        edge_kernel<<<grid, block, 0, stream>>>(
            (const uint4*)xb, edge_idx, edge_attr,
            W1, b1, W2, b2, out, n_edges);
    } else {
        edge_encoder_fp32<<<2048, 256, 0, stream>>>(
            x, edge_idx, edge_attr, W1, b1, W2, b2, out, n_edges);
    }
}

// Round 11
// 69.762 us; speedup vs baseline: 1.6855x; 1.4398x over previous
//
#include <hip/hip_runtime.h>
#include <stdint.h>

#define D_FEAT 128
#define H1 18
#define H2 32
#define EPS 1e-8f

typedef float f32x4 __attribute__((ext_vector_type(4)));
typedef float f32x2 __attribute__((ext_vector_type(2)));

// ---------- prep: x[f32,N,128] -> NORMALIZED fp8-e4m3 [N,128B] ----------
__global__ __launch_bounds__(256) void prep_kernel(
    const float* __restrict__ x,
    uint32_t* __restrict__ xq,   // [N][32] u32 : 4 fp8 per u32
    int n_nodes)
{
    const int lane = threadIdx.x & 63;
    const int sub = lane & 31;
    const int half = lane >> 5;
    const int wavesPerBlock = blockDim.x >> 6;
    const long long wv = (long long)blockIdx.x * wavesPerBlock + (threadIdx.x >> 6);
    const int node = (int)(2 * wv + half);
    if (node >= n_nodes) return;

    const f32x4 v = __builtin_nontemporal_load(
        reinterpret_cast<const f32x4*>(x + (size_t)node * D_FEAT) + sub);
    float ss = v[0] * v[0] + v[1] * v[1] + v[2] * v[2] + v[3] * v[3];
    #pragma unroll
    for (int m = 16; m >= 1; m >>= 1) ss += __shfl_xor(ss, m);
    const float r = 1.0f / fmaxf(sqrtf(ss), EPS);

    int p = 0;
    p = __builtin_amdgcn_cvt_pk_fp8_f32(v[0] * r, v[1] * r, p, false);
    p = __builtin_amdgcn_cvt_pk_fp8_f32(v[2] * r, v[3] * r, p, true);
    xq[(size_t)node * 32 + sub] = (uint32_t)p;
}

// fp8 e4m3 dot of 8 pairs (uint2 = 8 fp8 each), fp32 accumulate
__device__ __forceinline__ float dot8f8(uint2 s, uint2 t) {
    const f32x2 s0 = __builtin_amdgcn_cvt_pk_f32_fp8((int)s.x, false);
    const f32x2 s1 = __builtin_amdgcn_cvt_pk_f32_fp8((int)s.x, true);
    const f32x2 s2 = __builtin_amdgcn_cvt_pk_f32_fp8((int)s.y, false);
    const f32x2 s3 = __builtin_amdgcn_cvt_pk_f32_fp8((int)s.y, true);
    const f32x2 t0 = __builtin_amdgcn_cvt_pk_f32_fp8((int)t.x, false);
    const f32x2 t1 = __builtin_amdgcn_cvt_pk_f32_fp8((int)t.x, true);
    const f32x2 t2 = __builtin_amdgcn_cvt_pk_f32_fp8((int)t.y, false);
    const f32x2 t3 = __builtin_amdgcn_cvt_pk_f32_fp8((int)t.y, true);
    float d;
    d = s0[0] * t0[0];
    d = fmaf(s0[1], t0[1], d);
    d = fmaf(s1[0], t1[0], d);
    d = fmaf(s1[1], t1[1], d);
    d = fmaf(s2[0], t2[0], d);
    d = fmaf(s2[1], t2[1], d);
    d = fmaf(s3[0], t3[0], d);
    d = fmaf(s3[1], t3[1], d);
    return d;
}

// ---------- main: R8 skeleton, fp8 gathers (uint2/lane), weights via s_load ----------
__global__ __launch_bounds__(256) void edge_kernel(
    const uint2* __restrict__ xq,       // [N][16] (8 fp8 per uint2)
    const int* __restrict__ edge_index, // [2, E]
    const float* __restrict__ edge_attr,
    const float* __restrict__ W1, const float* __restrict__ b1,
    const float* __restrict__ W2, const float* __restrict__ b2,
    float* __restrict__ out, int n_edges)
{
    __shared__ int sIdx[4][2][64];
    __shared__ int tIdx[4][2][64];
    __shared__ float dotb[4][64];

    const int lane = threadIdx.x & 63;
    const int w = threadIdx.x >> 6;
    const int g = lane >> 4;
    const int k = lane & 15;
    const long long nBursts = ((long long)n_edges + 63) >> 6;
    const long long waveId = (long long)blockIdx.x * 4 + w;
    const long long bu0 = waveId * 2;
    const long long bu1 = bu0 + 1;
    if (bu0 >= nBursts) return;
    const bool have1 = bu1 < nBursts;

    const f32x4* __restrict__ eav = reinterpret_cast<const f32x4*>(edge_attr);
    const f32x4* __restrict__ W2v = reinterpret_cast<const f32x4*>(W2);
    const f32x4* __restrict__ b2v = reinterpret_cast<const f32x4*>(b2);

    // ---- stage burst0 indices + attr ----
    const long long e0 = (bu0 << 6) + lane;
    const bool act0 = e0 < (long long)n_edges;
    f32x4 attr0 = (f32x4)0.f;
    {
        int sL = 0, tL = 0;
        if (act0) {
            sL = edge_index[e0];
            tL = edge_index[(long long)n_edges + e0];
            attr0 = eav[e0];
        }
        sIdx[w][0][lane] = sL;
        tIdx[w][0][lane] = tL;
    }

    uint2 sA[4], tA[4], sB[4], tB[4];

    #define LOADB(BS, BT, BASE, BUF)                                      \
        _Pragma("unroll") for (int j = 0; j < 4; ++j) {                   \
            const int eg = (BASE + j) * 4 + g;                            \
            BS[j] = xq[(size_t)sIdx[w][BUF][eg] * 16 + k];                \
            BT[j] = xq[(size_t)tIdx[w][BUF][eg] * 16 + k];                \
        }
    #define CONSUME(BS, BT, BASE)                                         \
        _Pragma("unroll") for (int j = 0; j < 4; ++j) {                   \
            const int eg = (BASE + j) * 4 + g;                            \
            float d = dot8f8(BS[j], BT[j]);                               \
            d += __shfl_xor(d, 1);                                        \
            d += __shfl_xor(d, 2);                                        \
            d += __shfl_xor(d, 4);                                        \
            d += __shfl_xor(d, 8);                                        \
            if (k == 0) dotb[w][eg] = d;                                  \
        }
    #define MLP_STORE(ATTR, ACT, E)                                       \
        {                                                                 \
            const float cosv = dotb[w][lane];                             \
            float h[H1];                                                  \
            _Pragma("unroll") for (int i = 0; i < H1; ++i) {              \
                float v = b1[i];                                          \
                v = fmaf(ATTR[0], W1[0 * H1 + i], v);                     \
                v = fmaf(ATTR[1], W1[1 * H1 + i], v);                     \
                v = fmaf(ATTR[2], W1[2 * H1 + i], v);                     \
                v = fmaf(ATTR[3], W1[3 * H1 + i], v);                     \
                v = fmaf(cosv,    W1[4 * H1 + i], v);                     \
                h[i] = fmaxf(v, 0.f);                                     \
            }                                                             \
            if (ACT) {                                                    \
                f32x4* op = reinterpret_cast<f32x4*>(out + (size_t)(E) * H2); \
                _Pragma("unroll") for (int jg = 0; jg < 8; ++jg) {        \
                    f32x4 a = b2v[jg];                                    \
                    _Pragma("unroll") for (int i = 0; i < H1; ++i)        \
                        a += h[i] * W2v[i * 8 + jg];                      \
                    _Pragma("unroll") for (int c = 0; c < 4; ++c)         \
                        a[c] = fmaxf(a[c], 0.f);                          \
                    op[jg] = a;                                           \
                }                                                         \
            }                                                             \
        }

    // ---- burst0: issue first 16 gathers ----
    LOADB(sA, tA, 0, 0)
    LOADB(sB, tB, 4, 0)

    // ---- prefetch burst1 indices + attr while gathers are in flight ----
    const long long e1 = (bu1 << 6) + lane;
    const bool act1 = have1 && (e1 < (long long)n_edges);
    f32x4 attr1 = (f32x4)0.f;
    if (have1) {
        int sL = 0, tL = 0;
        if (act1) {
            sL = edge_index[e1];
            tL = edge_index[(long long)n_edges + e1];
            attr1 = eav[e1];
        }
        sIdx[w][1][lane] = sL;
        tIdx[w][1][lane] = tL;
    }

    // ---- burst0: consume/issue pipeline ----
    CONSUME(sA, tA, 0)
    LOADB(sA, tA, 8, 0)
    CONSUME(sB, tB, 4)
    LOADB(sB, tB, 12, 0)
    CONSUME(sA, tA, 8)
    CONSUME(sB, tB, 12)

    // ---- burst1: issue first 16 gathers BEFORE burst0's MLP ----
    if (have1) {
        LOADB(sA, tA, 0, 1)
        LOADB(sB, tB, 4, 1)
    }

    // ---- burst0 MLP + store (hides burst1 gather latency) ----
    MLP_STORE(attr0, act0, e0)

    if (!have1) return;

    // ---- burst1: finish pipeline ----
    CONSUME(sA, tA, 0)
    LOADB(sA, tA, 8, 1)
    CONSUME(sB, tB, 4)
    LOADB(sB, tB, 12, 1)
    CONSUME(sA, tA, 8)
    CONSUME(sB, tB, 12)

    MLP_STORE(attr1, act1, e1)

    #undef LOADB
    #undef CONSUME
    #undef MLP_STORE
}

// ---------- fallback (fp32 direct, known-good from round 1) ----------
__device__ __forceinline__ float mlp_out32(
    const float4 ea, float cosv,
    const float* __restrict__ sW1, const float* __restrict__ sb1,
    const float* __restrict__ sW2, const float* __restrict__ sb2,
    int sub, int base)
{
    const float f[5] = { ea.x, ea.y, ea.z, ea.w, cosv };
    float hval = 0.f;
    if (sub < H1) {
        hval = sb1[sub];
        #pragma unroll
        for (int kk = 0; kk < 5; ++kk) hval = fmaf(f[kk], sW1[kk * H1 + sub], hval);
        hval = fmaxf(hval, 0.f);
    }
    float acc = sb2[sub];
    #pragma unroll
    for (int i = 0; i < H1; ++i)
        acc = fmaf(__shfl(hval, base + i), sW2[i * H2 + sub], acc);
    return fmaxf(acc, 0.f);
}

__global__ __launch_bounds__(256) void edge_encoder_fp32(
    const float* __restrict__ x,
    const int* __restrict__ edge_index,
    const float* __restrict__ edge_attr,
    const float* __restrict__ W1, const float* __restrict__ b1,
    const float* __restrict__ W2, const float* __restrict__ b2,
    float* __restrict__ out, int n_edges)
{
    __shared__ float sW1[5 * H1];
    __shared__ float sb1[H1];
    __shared__ float sW2[H1 * H2];
    __shared__ float sb2[H2];
    for (int i = threadIdx.x; i < 5 * H1; i += blockDim.x) sW1[i] = W1[i];
    for (int i = threadIdx.x; i < H1; i += blockDim.x) sb1[i] = b1[i];
    for (int i = threadIdx.x; i < H1 * H2; i += blockDim.x) sW2[i] = W2[i];
    for (int i = threadIdx.x; i < H2; i += blockDim.x) sb2[i] = b2[i];
    __syncthreads();

    const int lane = threadIdx.x & 63;
    const int sub = lane & 31;
    const int base = lane & 32;
    const int wavesPerBlock = blockDim.x >> 6;
    const int waveId = blockIdx.x * wavesPerBlock + (threadIdx.x >> 6);
    const int totalWaves = gridDim.x * wavesPerBlock;

    for (long long gg = waveId; 2 * gg < (long long)n_edges; gg += totalWaves) {
        const long long e = 2 * gg + (lane >> 5);
        const bool active = (e < (long long)n_edges);
        float dot = 0.f, ss = 0.f, tt = 0.f;
        float4 ea = make_float4(0.f, 0.f, 0.f, 0.f);
        if (active) {
            const int srcN = edge_index[e];
            const int tgtN = edge_index[(long long)n_edges + e];
            const float4 s4 = *reinterpret_cast<const float4*>(
                x + (size_t)srcN * D_FEAT + (size_t)sub * 4);
            const float4 t4 = *reinterpret_cast<const float4*>(
                x + (size_t)tgtN * D_FEAT + (size_t)sub * 4);
            dot = s4.x * t4.x + s4.y * t4.y + s4.z * t4.z + s4.w * t4.w;
            ss  = s4.x * s4.x + s4.y * s4.y + s4.z * s4.z + s4.w * s4.w;
            tt  = t4.x * t4.x + t4.y * t4.y + t4.z * t4.z + t4.w * t4.w;
            ea = *reinterpret_cast<const float4*>(edge_attr + e * 4);
        }
        #pragma unroll
        for (int m = 16; m >= 1; m >>= 1) {
            dot += __shfl_xor(dot, m);
            ss  += __shfl_xor(ss, m);
            tt  += __shfl_xor(tt, m);
        }
        const float cosv = dot / (fmaxf(sqrtf(ss), EPS) * fmaxf(sqrtf(tt), EPS));
        const float o = mlp_out32(ea, cosv, sW1, sb1, sW2, sb2, sub, base);
        if (active) out[e * H2 + sub] = o;
    }
}

extern "C" void kernel_launch(void* const* d_in, const int* in_sizes, int n_in,
                              void* d_out, int out_size, void* d_ws, size_t ws_size,
                              hipStream_t stream) {
    const float* x         = (const float*)d_in[0];
    const int*   edge_idx  = (const int*)d_in[1];
    const float* edge_attr = (const float*)d_in[2];
    const float* W1        = (const float*)d_in[3];
    const float* b1        = (const float*)d_in[4];
    const float* W2        = (const float*)d_in[5];
    const float* b2        = (const float*)d_in[6];
    float* out = (float*)d_out;

    const int n_nodes = in_sizes[0] / D_FEAT;
    const int n_edges = in_sizes[1] / 2;

    const size_t xq_bytes = (size_t)n_nodes * D_FEAT;   // 1 byte per element

    if (ws_size >= xq_bytes) {
        uint32_t* xq = (uint32_t*)d_ws;
        const int block = 256;
        const int prep_grid = (n_nodes + 7) / 8;   // 2 nodes/wave, 8/block
        prep_kernel<<<prep_grid, block, 0, stream>>>(x, xq, n_nodes);

        const long long nBursts = ((long long)n_edges + 63) >> 6;
        const long long nWaves = (nBursts + 1) / 2;   // exactly 2 bursts/wave
        const int grid = (int)((nWaves + 3) / 4);
        edge_kernel<<<grid, block, 0, stream>>>(
            (const uint2*)xq, edge_idx, edge_attr,
            W1, b1, W2, b2, out, n_edges);
    } else {
        edge_encoder_fp32<<<2048, 256, 0, stream>>>(
            x, edge_idx, edge_attr, W1, b1, W2, b2, out, n_edges);
    }
}

// Round 12
// 63.905 us; speedup vs baseline: 1.8399x; 1.0917x over previous
//
#include <hip/hip_runtime.h>
#include <stdint.h>

#define D_FEAT 128
#define H1 18
#define H2 32
#define EPS 1e-8f

typedef float f32x4 __attribute__((ext_vector_type(4)));
typedef float f32x2 __attribute__((ext_vector_type(2)));

// ---------- prep: x[f32,N,128] -> NORMALIZED fp8-e4m3 [N,128B] ----------
__global__ __launch_bounds__(256) void prep_kernel(
    const float* __restrict__ x,
    uint32_t* __restrict__ xq,   // [N][32] u32 : 4 fp8 per u32
    int n_nodes)
{
    const int lane = threadIdx.x & 63;
    const int sub = lane & 31;
    const int half = lane >> 5;
    const int wavesPerBlock = blockDim.x >> 6;
    const long long wv = (long long)blockIdx.x * wavesPerBlock + (threadIdx.x >> 6);
    const int node = (int)(2 * wv + half);
    if (node >= n_nodes) return;

    const f32x4 v = __builtin_nontemporal_load(
        reinterpret_cast<const f32x4*>(x + (size_t)node * D_FEAT) + sub);
    float ss = v[0] * v[0] + v[1] * v[1] + v[2] * v[2] + v[3] * v[3];
    #pragma unroll
    for (int m = 16; m >= 1; m >>= 1) ss += __shfl_xor(ss, m);
    const float r = 1.0f / fmaxf(sqrtf(ss), EPS);

    int p = 0;
    p = __builtin_amdgcn_cvt_pk_fp8_f32(v[0] * r, v[1] * r, p, false);
    p = __builtin_amdgcn_cvt_pk_fp8_f32(v[2] * r, v[3] * r, p, true);
    xq[(size_t)node * 32 + sub] = (uint32_t)p;
}

// fp8 e4m3 dot of 8 pairs (uint2 = 8 fp8 each), fp32 accumulate
__device__ __forceinline__ float dot8f8(uint2 s, uint2 t) {
    const f32x2 s0 = __builtin_amdgcn_cvt_pk_f32_fp8((int)s.x, false);
    const f32x2 s1 = __builtin_amdgcn_cvt_pk_f32_fp8((int)s.x, true);
    const f32x2 s2 = __builtin_amdgcn_cvt_pk_f32_fp8((int)s.y, false);
    const f32x2 s3 = __builtin_amdgcn_cvt_pk_f32_fp8((int)s.y, true);
    const f32x2 t0 = __builtin_amdgcn_cvt_pk_f32_fp8((int)t.x, false);
    const f32x2 t1 = __builtin_amdgcn_cvt_pk_f32_fp8((int)t.x, true);
    const f32x2 t2 = __builtin_amdgcn_cvt_pk_f32_fp8((int)t.y, false);
    const f32x2 t3 = __builtin_amdgcn_cvt_pk_f32_fp8((int)t.y, true);
    float d;
    d = s0[0] * t0[0];
    d = fmaf(s0[1], t0[1], d);
    d = fmaf(s1[0], t1[0], d);
    d = fmaf(s1[1], t1[1], d);
    d = fmaf(s2[0], t2[0], d);
    d = fmaf(s2[1], t2[1], d);
    d = fmaf(s3[0], t3[0], d);
    d = fmaf(s3[1], t3[1], d);
    return d;
}

// ---------- main: ONE 64-edge burst per wave, fp8 gathers, 2-deep batch pipeline ----------
__global__ __launch_bounds__(256) void edge_kernel(
    const uint2* __restrict__ xq,       // [N][16] (8 fp8 per uint2)
    const int* __restrict__ edge_index, // [2, E]
    const float* __restrict__ edge_attr,
    const float* __restrict__ W1, const float* __restrict__ b1,
    const float* __restrict__ W2, const float* __restrict__ b2,
    float* __restrict__ out, int n_edges)
{
    __shared__ int sIdx[4][64];
    __shared__ int tIdx[4][64];
    __shared__ float dotb[4][64];

    const int lane = threadIdx.x & 63;
    const int w = threadIdx.x >> 6;
    const int g = lane >> 4;
    const int k = lane & 15;
    const long long nBursts = ((long long)n_edges + 63) >> 6;
    const long long burst = (long long)blockIdx.x * 4 + w;
    if (burst >= nBursts) return;

    const f32x4* __restrict__ eav = reinterpret_cast<const f32x4*>(edge_attr);
    const f32x4* __restrict__ W2v = reinterpret_cast<const f32x4*>(W2);
    const f32x4* __restrict__ b2v = reinterpret_cast<const f32x4*>(b2);

    // ---- stage indices + attr (lane = edge) ----
    const long long e = (burst << 6) + lane;
    const bool act = e < (long long)n_edges;
    f32x4 attr = (f32x4)0.f;
    {
        int sL = 0, tL = 0;
        if (act) {
            sL = edge_index[e];
            tL = edge_index[(long long)n_edges + e];
            attr = eav[e];
        }
        sIdx[w][lane] = sL;
        tIdx[w][lane] = tL;
    }

    uint2 sA[4], tA[4], sB[4], tB[4];

    #define LOADB(BS, BT, BASE)                                           \
        _Pragma("unroll") for (int j = 0; j < 4; ++j) {                   \
            const int eg = (BASE + j) * 4 + g;                            \
            BS[j] = xq[(size_t)sIdx[w][eg] * 16 + k];                     \
            BT[j] = xq[(size_t)tIdx[w][eg] * 16 + k];                     \
        }
    #define CONSUME(BS, BT, BASE)                                         \
        _Pragma("unroll") for (int j = 0; j < 4; ++j) {                   \
            const int eg = (BASE + j) * 4 + g;                            \
            float d = dot8f8(BS[j], BT[j]);                               \
            d += __shfl_xor(d, 1);                                        \
            d += __shfl_xor(d, 2);                                        \
            d += __shfl_xor(d, 4);                                        \
            d += __shfl_xor(d, 8);                                        \
            if (k == 0) dotb[w][eg] = d;                                  \
        }

    // ---- 2-deep rotating pipeline over 4-edge batches ----
    LOADB(sA, tA, 0)
    LOADB(sB, tB, 4)
    CONSUME(sA, tA, 0)
    LOADB(sA, tA, 8)
    CONSUME(sB, tB, 4)
    LOADB(sB, tB, 12)
    CONSUME(sA, tA, 8)
    CONSUME(sB, tB, 12)

    #undef LOADB
    #undef CONSUME

    const float cosv = dotb[w][lane];

    // ---- per-lane MLP: feats = {attr[0..3], cosv} ----
    float h[H1];
    #pragma unroll
    for (int i = 0; i < H1; ++i) {
        float v = b1[i];
        v = fmaf(attr[0], W1[0 * H1 + i], v);
        v = fmaf(attr[1], W1[1 * H1 + i], v);
        v = fmaf(attr[2], W1[2 * H1 + i], v);
        v = fmaf(attr[3], W1[3 * H1 + i], v);
        v = fmaf(cosv,    W1[4 * H1 + i], v);
        h[i] = fmaxf(v, 0.f);
    }

    if (act) {
        f32x4* op = reinterpret_cast<f32x4*>(out + (size_t)e * H2);
        #pragma unroll
        for (int jg = 0; jg < 8; ++jg) {
            f32x4 a = b2v[jg];
            #pragma unroll
            for (int i = 0; i < H1; ++i)
                a += h[i] * W2v[i * 8 + jg];
            #pragma unroll
            for (int c = 0; c < 4; ++c)
                a[c] = fmaxf(a[c], 0.f);
            op[jg] = a;
        }
    }
}

// ---------- fallback (fp32 direct, known-good from round 1) ----------
__device__ __forceinline__ float mlp_out32(
    const float4 ea, float cosv,
    const float* __restrict__ sW1, const float* __restrict__ sb1,
    const float* __restrict__ sW2, const float* __restrict__ sb2,
    int sub, int base)
{
    const float f[5] = { ea.x, ea.y, ea.z, ea.w, cosv };
    float hval = 0.f;
    if (sub < H1) {
        hval = sb1[sub];
        #pragma unroll
        for (int kk = 0; kk < 5; ++kk) hval = fmaf(f[kk], sW1[kk * H1 + sub], hval);
        hval = fmaxf(hval, 0.f);
    }
    float acc = sb2[sub];
    #pragma unroll
    for (int i = 0; i < H1; ++i)
        acc = fmaf(__shfl(hval, base + i), sW2[i * H2 + sub], acc);
    return fmaxf(acc, 0.f);
}

__global__ __launch_bounds__(256) void edge_encoder_fp32(
    const float* __restrict__ x,
    const int* __restrict__ edge_index,
    const float* __restrict__ edge_attr,
    const float* __restrict__ W1, const float* __restrict__ b1,
    const float* __restrict__ W2, const float* __restrict__ b2,
    float* __restrict__ out, int n_edges)
{
    __shared__ float sW1[5 * H1];
    __shared__ float sb1[H1];
    __shared__ float sW2[H1 * H2];
    __shared__ float sb2[H2];
    for (int i = threadIdx.x; i < 5 * H1; i += blockDim.x) sW1[i] = W1[i];
    for (int i = threadIdx.x; i < H1; i += blockDim.x) sb1[i] = b1[i];
    for (int i = threadIdx.x; i < H1 * H2; i += blockDim.x) sW2[i] = W2[i];
    for (int i = threadIdx.x; i < H2; i += blockDim.x) sb2[i] = b2[i];
    __syncthreads();

    const int lane = threadIdx.x & 63;
    const int sub = lane & 31;
    const int base = lane & 32;
    const int wavesPerBlock = blockDim.x >> 6;
    const int waveId = blockIdx.x * wavesPerBlock + (threadIdx.x >> 6);
    const int totalWaves = gridDim.x * wavesPerBlock;

    for (long long gg = waveId; 2 * gg < (long long)n_edges; gg += totalWaves) {
        const long long e = 2 * gg + (lane >> 5);
        const bool active = (e < (long long)n_edges);
        float dot = 0.f, ss = 0.f, tt = 0.f;
        float4 ea = make_float4(0.f, 0.f, 0.f, 0.f);
        if (active) {
            const int srcN = edge_index[e];
            const int tgtN = edge_index[(long long)n_edges + e];
            const float4 s4 = *reinterpret_cast<const float4*>(
                x + (size_t)srcN * D_FEAT + (size_t)sub * 4);
            const float4 t4 = *reinterpret_cast<const float4*>(
                x + (size_t)tgtN * D_FEAT + (size_t)sub * 4);
            dot = s4.x * t4.x + s4.y * t4.y + s4.z * t4.z + s4.w * t4.w;
            ss  = s4.x * s4.x + s4.y * s4.y + s4.z * s4.z + s4.w * s4.w;
            tt  = t4.x * t4.x + t4.y * t4.y + t4.z * t4.z + t4.w * t4.w;
            ea = *reinterpret_cast<const float4*>(edge_attr + e * 4);
        }
        #pragma unroll
        for (int m = 16; m >= 1; m >>= 1) {
            dot += __shfl_xor(dot, m);
            ss  += __shfl_xor(ss, m);
            tt  += __shfl_xor(tt, m);
        }
        const float cosv = dot / (fmaxf(sqrtf(ss), EPS) * fmaxf(sqrtf(tt), EPS));
        const float o = mlp_out32(ea, cosv, sW1, sb1, sW2, sb2, sub, base);
        if (active) out[e * H2 + sub] = o;
    }
}

extern "C" void kernel_launch(void* const* d_in, const int* in_sizes, int n_in,
                              void* d_out, int out_size, void* d_ws, size_t ws_size,
                              hipStream_t stream) {
    const float* x         = (const float*)d_in[0];
    const int*   edge_idx  = (const int*)d_in[1];
    const float* edge_attr = (const float*)d_in[2];
    const float* W1        = (const float*)d_in[3];
    const float* b1        = (const float*)d_in[4];
    const float* W2        = (const float*)d_in[5];
    const float* b2        = (const float*)d_in[6];
    float* out = (float*)d_out;

    const int n_nodes = in_sizes[0] / D_FEAT;
    const int n_edges = in_sizes[1] / 2;

    const size_t xq_bytes = (size_t)n_nodes * D_FEAT;   // 1 byte per element

    if (ws_size >= xq_bytes) {
        uint32_t* xq = (uint32_t*)d_ws;
        const int block = 256;
        const int prep_grid = (n_nodes + 7) / 8;   // 2 nodes/wave, 8/block
        prep_kernel<<<prep_grid, block, 0, stream>>>(x, xq, n_nodes);

        const long long nBursts = ((long long)n_edges + 63) >> 6;
        const int grid = (int)((nBursts + 3) / 4);   // exactly ONE burst per wave
        edge_kernel<<<grid, block, 0, stream>>>(
            (const uint2*)xq, edge_idx, edge_attr,
            W1, b1, W2, b2, out, n_edges);
    } else {
        edge_encoder_fp32<<<2048, 256, 0, stream>>>(
            x, edge_idx, edge_attr, W1, b1, W2, b2, out, n_edges);
    }
}